// Round 5
// baseline (822.371 us; speedup 1.0000x reference)
//
#include <hip/hip_runtime.h>
#include <hip/hip_bf16.h>
#include <hip/hip_fp16.h>
#include <math.h>

// Shapes: x [128,20000,1] f32; rows/cols [640000] i32; vals [640000] f32
// W_gc [20,10]; b_gc [10]; W_fc [200000,10]; b_fc [10]; out [128,10] f32.
//
// R18b: column-partitioned SpMM (gather/reduce split) to kill the cross-XCD
// line-service floor (~25us/step, 475us total = 80% of runtime).
//  - Old: row-CSR, every XCD re-gathers the whole 5.12MB plane from remote
//    L2s via LLC: ~41MB/step random 128B dirty-line service = 25us/step.
//  - New: edges partitioned by COLUMN half (NQ=2 per chunk). XCD role
//    (chunk c, col-half q) gathers only cols in its half -> the plane slice
//    it wrote itself last step (1.28MB, local L2). Row sums become dense
//    fp32 partials P[role][row][64] (nontemporal stores, no L2 pollution).
//    reduce_kernel (row-owner XCD) sums NQ partials + alpha/beta carry,
//    writes fp16 plane + fp32 carry LOCALLY -> next gather local again.
//  - CSR built once over virtual rows vr = q*N + row (hist/scan/scatter).
//  - proj_fc: R17 (1024-thr, wave-uniform scalar weights) unchanged, 56us.
//  - R18 compile fix: nontemporal builtins need native clang vectors, not
//    HIP_vector_type -> v4f = ext_vector_type(4) float.

#define NF 10
#define KCHEB 20
#define BCG 64                        // batch elems per chunk
#define COFF16 (KCHEB * BCG)          // 1280 fp16 elems per node in X16

typedef unsigned int u32;
typedef float v4f __attribute__((ext_vector_type(4)));

// ---------------- CSR build + small prep ----------------

__global__ void init_kernel(int* counts, float* h_part, const float* __restrict__ W_gc,
                            float* __restrict__ WgT, int N4, int H) {
    int i = blockIdx.x * blockDim.x + threadIdx.x;
    if (i < N4) counts[i] = 0;
    if (i < H) h_part[i] = 0.f;
    if (i < KCHEB * NF) WgT[(i % NF) * KCHEB + (i / NF)] = W_gc[i];  // [j][k]
}

__global__ void hist_kernel(const int* __restrict__ rows, const int* __restrict__ cols,
                            int* __restrict__ counts, int E, int N, int QS) {
    int e = blockIdx.x * blockDim.x + threadIdx.x;
    if (e < E) {
        int q = cols[e] / QS;
        atomicAdd(&counts[q * N + rows[e]], 1);
    }
}

#define SCAN_THREADS 1024
__global__ void scan_kernel(const int* __restrict__ counts, int* __restrict__ row_start,
                            int* __restrict__ cursor, int N4) {
    __shared__ int sh[SCAN_THREADS];
    int t = threadIdx.x;
    int CH = (N4 + SCAN_THREADS - 1) / SCAN_THREADS;
    int base = t * CH;
    int sum = 0;
    for (int i = 0; i < CH; ++i) {
        int idx = base + i;
        sum += (idx < N4) ? counts[idx] : 0;
    }
    sh[t] = sum;
    __syncthreads();
    for (int off = 1; off < SCAN_THREADS; off <<= 1) {
        int v = (t >= off) ? sh[t - off] : 0;
        __syncthreads();
        sh[t] += v;
        __syncthreads();
    }
    int run = (t == 0) ? 0 : sh[t - 1];
    for (int i = 0; i < CH; ++i) {
        int idx = base + i;
        if (idx < N4) {
            int v = counts[idx];
            row_start[idx] = run;
            cursor[idx] = run;
            run += v;
        }
    }
    if (t == SCAN_THREADS - 1) row_start[N4] = run;
}

// csr[p] = (col*COFF16 [element offset of node's X16 row], bits(val))
__global__ void scatter_kernel(const int* __restrict__ rows, const int* __restrict__ cols,
                               const float* __restrict__ vals, int* __restrict__ cursor,
                               int2* __restrict__ csr, int E, int N, int QS) {
    int e = blockIdx.x * blockDim.x + threadIdx.x;
    if (e >= E) return;
    int col = cols[e];
    int q = col / QS;
    int p = atomicAdd(&cursor[q * N + rows[e]], 1);
    csr[p] = make_int2(col * COFF16, __float_as_int(vals[e]));
}

// ---------------- T0 fill (tiled transpose; fp16 plane 0 + fp32 carry 0) ----

__global__ void transpose_kernel(const float* __restrict__ x, __half* __restrict__ X16,
                                 float* __restrict__ C32, int N, int ntiles, int b0s) {
    __shared__ float tile[BCG][65];
    int tid = threadIdx.x;
    int g = blockIdx.x / ntiles;
    int ti = blockIdx.x - g * ntiles;
    int n0 = ti * 64;
#pragma unroll
    for (int p = 0; p < 16; ++p) {
        int idx = p * 256 + tid;
        int row = idx >> 6;        // batch offset 0..63
        int col = idx & 63;        // node offset 0..63
        if (n0 + col < N)
            tile[row][col] = x[(size_t)(b0s + g * BCG + row) * N + n0 + col];
    }
    __syncthreads();
#pragma unroll
    for (int p = 0; p < 16; ++p) {
        int idx = p * 256 + tid;
        int nloc = idx >> 6;       // node offset 0..63
        int bb = idx & 63;         // batch offset 0..63
        int n = n0 + nloc;
        if (n < N) {
            float v = tile[bb][nloc];
            X16[(size_t)(g * N + n) * COFF16 + bb] = __float2half_rn(v);   // plane k=0
            C32[((size_t)(g * 2 + 0) * N + n) * BCG + bb] = v;             // carry slot 0
        }
    }
}

// ---------------- SpMM gather phase ----------------
// Block = 256 thr = 32 vrows x 8 bq lanes. XCD role (c,q) gathers only cols
// in its quarter (local L2 slice). Writes fp32 partials nontemporally.

__global__ __launch_bounds__(256)
void gather_kernel(const __half* __restrict__ X16, float* __restrict__ P,
                   const int* __restrict__ row_start4, const int2* __restrict__ csr4,
                   int N, int kIn, int nqMask, int nqSh, int gMask, int hSh, int twSh) {
    int xcd = blockIdx.x & 7;
    int sub = blockIdx.x >> 3;
    int q = xcd & nqMask;
    int c = (xcd >> nqSh) & gMask;
    int h = xcd >> hSh;
    int tid = threadIdx.x;
    int ln = tid >> 3;             // vrow 0..31
    int bq = tid & 7;
    int r = ((sub << twSh) + h) * 32 + ln;
    if (r >= N) return;
    int vr = q * N + r;
    int s = row_start4[vr];
    int e = row_start4[vr + 1];

    const __half* gin = X16 + (size_t)c * N * COFF16;
    int koff = kIn * BCG + bq * 8;
    float acc[8];
#pragma unroll
    for (int t = 0; t < 8; ++t) acc[t] = 0.f;

    int i = s;
    for (; i + 4 <= e; i += 4) {
        int2 p0 = csr4[i], p1 = csr4[i + 1], p2 = csr4[i + 2], p3 = csr4[i + 3];
        uint4 u0 = *(const uint4*)(gin + p0.x + koff);
        uint4 u1 = *(const uint4*)(gin + p1.x + koff);
        uint4 u2 = *(const uint4*)(gin + p2.x + koff);
        uint4 u3 = *(const uint4*)(gin + p3.x + koff);
        float v0 = __int_as_float(p0.y), v1 = __int_as_float(p1.y);
        float v2 = __int_as_float(p2.y), v3 = __int_as_float(p3.y);
        {
            float2 f0 = __half22float2(*(__half2*)&u0.x), f1 = __half22float2(*(__half2*)&u0.y);
            float2 f2 = __half22float2(*(__half2*)&u0.z), f3 = __half22float2(*(__half2*)&u0.w);
            acc[0] += v0 * f0.x; acc[1] += v0 * f0.y; acc[2] += v0 * f1.x; acc[3] += v0 * f1.y;
            acc[4] += v0 * f2.x; acc[5] += v0 * f2.y; acc[6] += v0 * f3.x; acc[7] += v0 * f3.y;
        }
        {
            float2 f0 = __half22float2(*(__half2*)&u1.x), f1 = __half22float2(*(__half2*)&u1.y);
            float2 f2 = __half22float2(*(__half2*)&u1.z), f3 = __half22float2(*(__half2*)&u1.w);
            acc[0] += v1 * f0.x; acc[1] += v1 * f0.y; acc[2] += v1 * f1.x; acc[3] += v1 * f1.y;
            acc[4] += v1 * f2.x; acc[5] += v1 * f2.y; acc[6] += v1 * f3.x; acc[7] += v1 * f3.y;
        }
        {
            float2 f0 = __half22float2(*(__half2*)&u2.x), f1 = __half22float2(*(__half2*)&u2.y);
            float2 f2 = __half22float2(*(__half2*)&u2.z), f3 = __half22float2(*(__half2*)&u2.w);
            acc[0] += v2 * f0.x; acc[1] += v2 * f0.y; acc[2] += v2 * f1.x; acc[3] += v2 * f1.y;
            acc[4] += v2 * f2.x; acc[5] += v2 * f2.y; acc[6] += v2 * f3.x; acc[7] += v2 * f3.y;
        }
        {
            float2 f0 = __half22float2(*(__half2*)&u3.x), f1 = __half22float2(*(__half2*)&u3.y);
            float2 f2 = __half22float2(*(__half2*)&u3.z), f3 = __half22float2(*(__half2*)&u3.w);
            acc[0] += v3 * f0.x; acc[1] += v3 * f0.y; acc[2] += v3 * f1.x; acc[3] += v3 * f1.y;
            acc[4] += v3 * f2.x; acc[5] += v3 * f2.y; acc[6] += v3 * f3.x; acc[7] += v3 * f3.y;
        }
    }
    for (; i < e; ++i) {
        int2 p0 = csr4[i];
        uint4 u0 = *(const uint4*)(gin + p0.x + koff);
        float v0 = __int_as_float(p0.y);
        float2 f0 = __half22float2(*(__half2*)&u0.x), f1 = __half22float2(*(__half2*)&u0.y);
        float2 f2 = __half22float2(*(__half2*)&u0.z), f3 = __half22float2(*(__half2*)&u0.w);
        acc[0] += v0 * f0.x; acc[1] += v0 * f0.y; acc[2] += v0 * f1.x; acc[3] += v0 * f1.y;
        acc[4] += v0 * f2.x; acc[5] += v0 * f2.y; acc[6] += v0 * f3.x; acc[7] += v0 * f3.y;
    }

    float* pp = P + ((size_t)((c << nqSh) + q) * N + r) * BCG + bq * 8;
    v4f a0 = { acc[0], acc[1], acc[2], acc[3] };
    v4f a1 = { acc[4], acc[5], acc[6], acc[7] };
    __builtin_nontemporal_store(a0, (v4f*)pp);
    __builtin_nontemporal_store(a1, (v4f*)(pp + 4));
}

// ---------------- SpMM reduce phase ----------------
// Row-owner XCD sums NQ partials (nontemporal reads, no L2 pollution),
// applies alpha/beta with fp32 carry, writes fp16 plane + carry LOCALLY.

__global__ __launch_bounds__(256)
void reduce_kernel(__half* __restrict__ X16, float* __restrict__ C32,
                   const float* __restrict__ P,
                   int N, int QS, int NQ, int nqMask, int nqSh, int gMask, int hSh, int twSh,
                   int kOut, float alpha, float beta) {
    int xcd = blockIdx.x & 7;
    int sub = blockIdx.x >> 3;
    int q = xcd & nqMask;
    int c = (xcd >> nqSh) & gMask;
    int h = xcd >> hSh;
    int tid = threadIdx.x;
    int ln = tid >> 3;
    int bq = tid & 7;
    int r = q * QS + ((sub << twSh) + h) * 32 + ln;
    int rend = (q + 1) * QS; if (rend > N) rend = N;
    if (r >= rend) return;
    int bo = bq * 8;

    float acc[8];
#pragma unroll
    for (int t = 0; t < 8; ++t) acc[t] = 0.f;
    for (int qq = 0; qq < NQ; ++qq) {
        const float* pp = P + ((size_t)((c << nqSh) + qq) * N + r) * BCG + bo;
        v4f a0 = __builtin_nontemporal_load((const v4f*)pp);
        v4f a1 = __builtin_nontemporal_load((const v4f*)(pp + 4));
        acc[0] += a0.x; acc[1] += a0.y; acc[2] += a0.z; acc[3] += a0.w;
        acc[4] += a1.x; acc[5] += a1.y; acc[6] += a1.z; acc[7] += a1.w;
    }

    float* cslot = C32 + ((size_t)(c * 2 + (kOut & 1)) * N + r) * BCG + bo;
    float o[8];
#pragma unroll
    for (int t = 0; t < 8; ++t) o[t] = alpha * acc[t];
    if (beta != 0.f) {
        const float4 pv0 = *(const float4*)(cslot);
        const float4 pv1 = *(const float4*)(cslot + 4);
        o[0] += beta * pv0.x; o[1] += beta * pv0.y; o[2] += beta * pv0.z; o[3] += beta * pv0.w;
        o[4] += beta * pv1.x; o[5] += beta * pv1.y; o[6] += beta * pv1.z; o[7] += beta * pv1.w;
    }
    *(float4*)(cslot)     = make_float4(o[0], o[1], o[2], o[3]);
    *(float4*)(cslot + 4) = make_float4(o[4], o[5], o[6], o[7]);
    __half* o16 = X16 + (size_t)(c * N + r) * COFF16 + kOut * BCG + bo;
    uint4 h4;
    __half2 h01 = __floats2half2_rn(o[0], o[1]);
    __half2 h23 = __floats2half2_rn(o[2], o[3]);
    __half2 h45 = __floats2half2_rn(o[4], o[5]);
    __half2 h67 = __floats2half2_rn(o[6], o[7]);
    h4.x = *(u32*)&h01; h4.y = *(u32*)&h23; h4.z = *(u32*)&h45; h4.w = *(u32*)&h67;
    *(uint4*)o16 = h4;
}

// ---------------- Fused projection + FC partial ----------------
// Block = 1024 thr = 16 waves; wave = one node x 64 bb lanes. All weight reads
// wave-uniform -> scalar loads on SMEM pipe. 2 blocks/CU = 32 waves/CU.

__global__ __launch_bounds__(1024, 8)
void proj_fc_kernel(const __half* __restrict__ X16,
                    const float* __restrict__ WgT,    // [j][k] = [10][20]
                    const float* __restrict__ b_gc,
                    const float* __restrict__ W_fc,
                    float* __restrict__ h_part,
                    int N, int b0s, int G) {
    __shared__ float sRed[BCG * 11];
    int tid = threadIdx.x;
    for (int i = tid; i < BCG * 11; i += 1024) sRed[i] = 0.f;
    __syncthreads();

    int g = blockIdx.x % G;
    int bidx = blockIdx.x / G;
    int nblk = gridDim.x / G;

    int bb = tid & (BCG - 1);
    int wv = __builtin_amdgcn_readfirstlane(tid >> 6);   // wave slot 0..15, uniform

    float h_loc[NF];
#pragma unroll
    for (int f = 0; f < NF; ++f) h_loc[f] = 0.f;

    const __half* chunkBase = X16 + (size_t)g * N * COFF16;
    int ngroups = (N + 15) / 16;
    for (int grp = bidx; grp < ngroups; grp += nblk) {
        int n = grp * 16 + wv;                           // uniform per wave
        if (n < N) {
            float xt[KCHEB];
            const __half* xp = chunkBase + (size_t)n * COFF16 + bb;
#pragma unroll
            for (int k = 0; k < KCHEB; ++k) xt[k] = __half2float(xp[k * BCG]);

            const float* wfBase = W_fc + (size_t)n * (NF * NF);
#pragma unroll 1
            for (int j = 0; j < NF; ++j) {
                const float* wg = WgT + j * KCHEB;       // 16B-aligned, contiguous 20f
                float gc = b_gc[j];
#pragma unroll
                for (int k = 0; k < KCHEB; ++k) gc += wg[k] * xt[k];
                gc = fmaxf(gc, 0.f);
                const float* wf = wfBase + j * NF;       // 8B-aligned, contiguous 10f
#pragma unroll
                for (int f = 0; f < NF; ++f) h_loc[f] += gc * wf[f];
            }
        }
    }
#pragma unroll
    for (int f = 0; f < NF; ++f) atomicAdd(&sRed[bb * 11 + f], h_loc[f]);
    __syncthreads();
    for (int i = tid; i < BCG * NF; i += 1024) {
        int rb = i / NF;
        int rf = i - rb * NF;
        atomicAdd(&h_part[(size_t)(b0s + g * BCG + rb) * NF + rf], sRed[rb * 11 + rf]);
    }
}

// ---------------- Bias + ReLU + softmax ----------------

__global__ void softmax_kernel(const float* __restrict__ h_part, const float* __restrict__ b_fc,
                               float* __restrict__ out, int B) {
    int b = blockIdx.x * blockDim.x + threadIdx.x;
    if (b >= B) return;
    float v[NF];
    float m = -1e30f;
#pragma unroll
    for (int f = 0; f < NF; ++f) {
        float t = fmaxf(h_part[b * NF + f] + b_fc[f], 0.f);
        v[f] = t;
        m = fmaxf(m, t);
    }
    float s = 0.f;
#pragma unroll
    for (int f = 0; f < NF; ++f) { v[f] = expf(v[f] - m); s += v[f]; }
    float inv = 1.f / s;
#pragma unroll
    for (int f = 0; f < NF; ++f) out[b * NF + f] = v[f] * inv;
}

// ---------------- launch ----------------

static inline int ilog2i(int v) { int s = 0; while ((1 << s) < v) ++s; return s; }

extern "C" void kernel_launch(void* const* d_in, const int* in_sizes, int n_in,
                              void* d_out, int out_size, void* d_ws, size_t ws_size,
                              hipStream_t stream) {
    const float* x    = (const float*)d_in[0];
    const int*   rows = (const int*)d_in[1];
    const int*   cols = (const int*)d_in[2];
    const float* vals = (const float*)d_in[3];
    const float* W_gc = (const float*)d_in[4];
    const float* b_gc = (const float*)d_in[5];
    const float* W_fc = (const float*)d_in[6];
    const float* b_fc = (const float*)d_in[7];
    float* out = (float*)d_out;

    const int E = in_sizes[1];
    const int N = in_sizes[6] / (NF * NF);
    const int B = in_sizes[0] / N;

    // ---- workspace carve (counts/cursor/row_start sized for NQ up to 8) ----
    char* p = (char*)d_ws;
    int* counts    = (int*)p;   p += sizeof(int) * (size_t)(8 * N);
    int* row_start = (int*)p;   p += sizeof(int) * (size_t)(8 * N + 1);
    int* cursor    = (int*)p;   p += sizeof(int) * (size_t)(8 * N);
    p = (char*)(((size_t)p + 15) & ~(size_t)15);
    int2* csr      = (int2*)p;  p += sizeof(int2) * (size_t)E;
    float* h_part  = (float*)p; p += sizeof(float) * (size_t)B * NF;
    p = (char*)(((size_t)p + 15) & ~(size_t)15);
    float* WgT     = (float*)p; p += sizeof(float) * (size_t)(NF * KCHEB);
    size_t fixed = (size_t)(p - (char*)d_ws);
    fixed = (fixed + 255) & ~(size_t)255;

    size_t perChunk16 = (size_t)N * COFF16 * sizeof(__half);     // 51.2 MB
    size_t perCarry   = (size_t)2 * N * BCG * sizeof(float);     // 10.24 MB
    size_t perP       = (size_t)N * BCG * sizeof(float);         // 5.12 MB per role

    // Config cascade: (G, NQ). Partials size = G*NQ*perP.
    int G = (B >= 2 * BCG) ? 2 : 1;
    int NQ = (G == 2) ? 2 : 8;
    while (fixed + (size_t)G * (perChunk16 + perCarry) + (size_t)G * NQ * perP > ws_size) {
        if (G == 2) { G = 1; NQ = 8; }
        else if (NQ > 1) { NQ >>= 1; }
        else break;  // minimal config; proceed regardless
    }
    __half* X16 = (__half*)((char*)d_ws + fixed);
    size_t x16b = ((size_t)G * perChunk16 + 255) & ~(size_t)255;
    float* C32 = (float*)((char*)d_ws + fixed + x16b);
    size_t c32b = ((size_t)G * perCarry + 255) & ~(size_t)255;
    float* P = (float*)((char*)d_ws + fixed + x16b + c32b);

    int BT = G * BCG;
    int nsc = B / BT;
    int QS = (N + NQ - 1) / NQ;
    int N4 = NQ * N;
    int TW = 8 / (G * NQ);           // twin XCDs per role
    int nqSh = ilog2i(NQ);
    int gSh  = ilog2i(G);
    int twSh = ilog2i(TW);
    int hSh  = nqSh + gSh;
    int nqMask = NQ - 1;
    int gMask  = G - 1;

    // ---- CSR build (once) + WgT prep ----
    {
        int H = B * NF;
        int cov = (N4 > H) ? N4 : H;
        init_kernel<<<(cov + 255) / 256, 256, 0, stream>>>(counts, h_part, W_gc, WgT, N4, H);
        hist_kernel<<<(E + 255) / 256, 256, 0, stream>>>(rows, cols, counts, E, N, QS);
        scan_kernel<<<1, SCAN_THREADS, 0, stream>>>(counts, row_start, cursor, N4);
        scatter_kernel<<<(E + 255) / 256, 256, 0, stream>>>(rows, cols, vals, cursor, csr, E, N, QS);
    }

    int ntiles = (N + 63) / 64;
    int subsG = (N + 32 * TW - 1) / (32 * TW);
    int subsR = (QS + 32 * TW - 1) / (32 * TW);
    int gridGather = 8 * subsG;
    int gridReduce = 8 * subsR;

    for (int c = 0; c < nsc; ++c) {
        int b0s = c * BT;
        transpose_kernel<<<G * ntiles, 256, 0, stream>>>(x, X16, C32, N, ntiles, b0s);
        for (int k = 1; k < KCHEB; ++k) {
            float alpha = (k == 1) ? 1.f : 2.f;
            float beta  = (k == 1) ? 0.f : -1.f;
            gather_kernel<<<gridGather, 256, 0, stream>>>(
                X16, P, row_start, csr, N, k - 1, nqMask, nqSh, gMask, hSh, twSh);
            reduce_kernel<<<gridReduce, 256, 0, stream>>>(
                X16, C32, P, N, QS, NQ, nqMask, nqSh, gMask, hSh, twSh,
                k, alpha, beta);
        }
        proj_fc_kernel<<<256 * G, 1024, 0, stream>>>(X16, WgT, b_gc, W_fc, h_part, N, b0s, G);
    }

    softmax_kernel<<<1, 128, 0, stream>>>(h_part, b_fc, out, B);
}